// Round 7
// baseline (134.174 us; speedup 1.0000x reference)
//
#include <hip/hip_runtime.h>
#include <math.h>

// Problem constants
#define B_  4
#define T_  2048
#define C_  1024
#define HS_ 64
#define M_  (B_*T_)   // 8192 rows
#define NCAT 192
#define SCALE_ 0.03125f   // C^-0.5

typedef unsigned short ushort_t;
typedef short bf16x8 __attribute__((ext_vector_type(8)));
typedef float f32x4 __attribute__((ext_vector_type(4)));

static __device__ __forceinline__ unsigned short f2bf(float f) {   // RNE (for inputs)
    union { float f; unsigned int u; } c; c.f = f;
    unsigned int u = c.u;
    return (unsigned short)((u + 0x7FFFu + ((u >> 16) & 1u)) >> 16);
}
static __device__ __forceinline__ unsigned short f2bf_fast(float f) { // 2-op round
    union { float f; unsigned int u; } c; c.f = f;
    return (unsigned short)((c.u + 0x8000u) >> 16);
}

// ---------------------------------------------------------------------------
// Kernel 1: W -> wt bf16 transposed [192][1024] (4/thread, 192 blocks).
// ---------------------------------------------------------------------------
__global__ void wconv_kernel(const float* __restrict__ Wq, const float* __restrict__ Wk,
                             const float* __restrict__ Wv, ushort_t* __restrict__ wt) {
    int idx = (blockIdx.x * 256 + threadIdx.x) * 4;   // < 192*1024
    int n = idx >> 10;
    int k0 = idx & 1023;
    const float* W = (n < 64) ? Wq : (n < 128) ? Wk : Wv;
    int nn = n & 63;
    ushort_t o0 = f2bf(W[(k0 + 0) * HS_ + nn]);
    ushort_t o1 = f2bf(W[(k0 + 1) * HS_ + nn]);
    ushort_t o2 = f2bf(W[(k0 + 2) * HS_ + nn]);
    ushort_t o3 = f2bf(W[(k0 + 3) * HS_ + nn]);
    uint2 d;
    d.x = (unsigned)o0 | ((unsigned)o1 << 16);
    d.y = (unsigned)o2 | ((unsigned)o3 << 16);
    *(uint2*)(wt + (size_t)n * C_ + k0) = d;
}

// ---------------------------------------------------------------------------
// Kernel 2: QKV projection, LDS-STAGED canonical GEMM (replaces the
// scatter-load version: every old load instruction gathered 16 lines at
// 2-4 KB stride; ~8x over roofline). Block = 32 rows x 192 cols, 512 thr
// = 8 waves (2 m-tiles x 4 n-slices of 48). K-loop 8 x BK=128:
//   reg-stage 8 coalesced 16B global loads/thread -> barrier ->
//   LDS write (rows padded to 136 elems = 272 B; bank aliasing <= 2-way,
//   free per m136) -> barrier -> 4x{1 A-frag + 3 B-frag b128 reads, 3 MFMA}.
// Fragment k-layout (qd*8+i*32) and C->(row=qd*4+r, col=lq) epilogue are
// IDENTICAL to the verified kernel. Global traffic 228->128 MB, all
// consecutive-lane coalesced. Grid 256 blocks = 1/CU.
// Q pre-scaled. V transposed [b][d][t].
// ---------------------------------------------------------------------------
__global__ __launch_bounds__(512, 2) void proj_kernel(const float* __restrict__ x,
    const ushort_t* __restrict__ wt,
    ushort_t* __restrict__ qws, ushort_t* __restrict__ kws, ushort_t* __restrict__ vt) {
    // xs[32][136] + ws[192][136] bf16, padded rows (272 B) = 60928 B
    __shared__ __align__(16) ushort_t lds[32 * 136 + 192 * 136];
    ushort_t* xs  = lds;
    ushort_t* wsl = lds + 32 * 136;

    int tid  = threadIdx.x;
    int wid  = tid >> 6;
    int lane = tid & 63;
    int qd   = lane >> 4;
    int lq   = lane & 15;
    int mi   = wid >> 2;       // m-tile 0..1 (16 rows each)
    int nj   = wid & 3;        // n-slice 0..3 (48 cols = 3 tiles each)
    int r0   = blockIdx.x * 32;

    f32x4 acc[3];
    #pragma unroll
    for (int i = 0; i < 3; i++) acc[i] = (f32x4){0.f,0.f,0.f,0.f};

    // staging chunk ids (constant across K-steps)
    int xrow0 = tid >> 5,  xc0 = (tid & 31);            // chunk t
    int xrow1 = (tid + 512) >> 5, xc1 = ((tid + 512) & 31);

    for (int ks = 0; ks < 8; ks++) {
        // ---- reg-stage global loads (coalesced; fly during other waves' tail)
        float4 xv0 = *(const float4*)(x + (size_t)(r0 + xrow0) * C_ + ks * 128 + xc0 * 4);
        float4 xv1 = *(const float4*)(x + (size_t)(r0 + xrow1) * C_ + ks * 128 + xc1 * 4);
        uint4 wv[6];
        #pragma unroll
        for (int j = 0; j < 6; j++) {
            int cid = tid + j * 512;            // 0..3071
            int n   = cid >> 4, c16 = cid & 15;
            wv[j] = *(const uint4*)(wt + (size_t)n * C_ + ks * 128 + c16 * 8);
        }
        __syncthreads();    // previous step's LDS reads complete
        {
            uint2 p0, p1;
            p0.x = (unsigned)f2bf(xv0.x) | ((unsigned)f2bf(xv0.y) << 16);
            p0.y = (unsigned)f2bf(xv0.z) | ((unsigned)f2bf(xv0.w) << 16);
            p1.x = (unsigned)f2bf(xv1.x) | ((unsigned)f2bf(xv1.y) << 16);
            p1.y = (unsigned)f2bf(xv1.z) | ((unsigned)f2bf(xv1.w) << 16);
            *(uint2*)(xs + xrow0 * 136 + xc0 * 4) = p0;
            *(uint2*)(xs + xrow1 * 136 + xc1 * 4) = p1;
            #pragma unroll
            for (int j = 0; j < 6; j++) {
                int cid = tid + j * 512;
                int n   = cid >> 4, c16 = cid & 15;
                *(uint4*)(wsl + n * 136 + c16 * 8) = wv[j];
            }
        }
        __syncthreads();    // tile staged

        // ---- compute: 4 k-subiters x 3 n-tiles
        const ushort_t* xrow = xs + (mi * 16 + lq) * 136;
        #pragma unroll
        for (int i = 0; i < 4; i++) {
            bf16x8 af = *(const bf16x8*)(xrow + qd * 8 + i * 32);
            #pragma unroll
            for (int nt = 0; nt < 3; nt++) {
                bf16x8 bv = *(const bf16x8*)(wsl + (nj * 48 + nt * 16 + lq) * 136 + qd * 8 + i * 32);
                acc[nt] = __builtin_amdgcn_mfma_f32_16x16x32_bf16(af, bv, acc[nt], 0, 0, 0);
            }
        }
    }

    // ---- epilogue: identical mapping to verified kernel ----
    #pragma unroll
    for (int nt = 0; nt < 3; nt++) {
        int n    = nj * 48 + nt * 16 + lq;   // 0..191
        int outn = n >> 6;                   // 0=Q 1=K 2=V
        int col  = n & 63;
        #pragma unroll
        for (int r = 0; r < 4; r++) {
            int row = r0 + mi * 16 + qd * 4 + r;
            float v = acc[nt][r];
            if (outn == 0) v *= SCALE_;           // pre-scale Q
            ushort_t val = f2bf(v);
            if (outn == 0)      qws[(size_t)row * HS_ + col] = val;
            else if (outn == 1) kws[(size_t)row * HS_ + col] = val;
            else {
                int b = row >> 11, t = row & 2047;
                vt[((size_t)b * 64 + col) * T_ + t] = val;
            }
        }
    }
}

// ---------------------------------------------------------------------------
// Kernel 3: balanced-pair causal flash, 512-thread blocks (8 waves).
// (Verified R6 structure, unchanged.)
// ---------------------------------------------------------------------------
__global__ __launch_bounds__(512, 2) void flash_kernel(const ushort_t* __restrict__ qws,
    const ushort_t* __restrict__ kws, const ushort_t* __restrict__ vt,
    float* __restrict__ out) {
    // pool: during k-loop = per-wave Pw[8][16*72] bf16 (18432 B);
    // after k-loop (sync'd) = f32x4 red[4][4*64] (16384 B) + float lred[4][64]
    __shared__ __align__(16) unsigned char pool[18432];

    int tid  = threadIdx.x;
    int wid  = tid >> 6;      // 0..7
    int lane = tid & 63;
    int qd   = lane >> 4;
    int lq   = lane & 15;
    int ts   = wid >> 2;      // 0 = tile p, 1 = tile 127-p
    int ws   = wid & 3;       // key-slice 0..3

    int batch = blockIdx.y;
    int p     = blockIdx.x;
    int tile  = ts ? (127 - p) : p;
    int q0    = tile * 16;
    int qrow  = q0 + lq;
    int grow  = batch * T_ + qrow;
    int nU    = (tile + 4) >> 2;    // 64-key units covering keys [0, q0+16)

    bf16x8 qf[2];
    #pragma unroll
    for (int st = 0; st < 2; st++)
        qf[st] = *(const bf16x8*)(qws + (size_t)grow * HS_ + st * 32 + qd * 8);

    float lsum = 0.f;
    f32x4 O[4];
    #pragma unroll
    for (int nt = 0; nt < 4; nt++) O[nt] = (f32x4){0.f,0.f,0.f,0.f};

    ushort_t* pw = (ushort_t*)pool + wid * 1152 + lq * 72;   // stride 72 bf16
    const ushort_t* kp    = kws + (size_t)batch * T_ * HS_;
    const ushort_t* vbase = vt  + (size_t)batch * 64 * T_;

    for (int u = ws; u < nU; u += 4) {
        int kb = u * 64;

        // batched loads: 8 K-frags + 8 V-frags, all 16 independent & in flight
        bf16x8 kf[8], vf[8];
        #pragma unroll
        for (int sub = 0; sub < 4; sub++)
            #pragma unroll
            for (int st = 0; st < 2; st++)
                kf[sub * 2 + st] = *(const bf16x8*)(kp + (size_t)(kb + sub * 16 + lq) * HS_ + st * 32 + qd * 8);
        #pragma unroll
        for (int nt = 0; nt < 4; nt++)
            #pragma unroll
            for (int kk = 0; kk < 2; kk++)
                vf[nt * 2 + kk] = *(const bf16x8*)(vbase + ((size_t)nt * 16 + lq) * T_ + kb + kk * 32 + qd * 8);

        // S^T = K . Q^T (Q pre-scaled): 4 sub-tiles of 16 keys
        f32x4 S[4];
        #pragma unroll
        for (int sub = 0; sub < 4; sub++) {
            f32x4 s = (f32x4){0.f,0.f,0.f,0.f};
            #pragma unroll
            for (int st = 0; st < 2; st++)
                s = __builtin_amdgcn_mfma_f32_16x16x32_bf16(kf[sub * 2 + st], qf[st], s, 0, 0, 0);
            S[sub] = s;
        }

        // P = exp(S); mask only when this 64-key unit can cross the diagonal
        if (kb + 64 > q0) {
            #pragma unroll
            for (int sub = 0; sub < 4; sub++)
                #pragma unroll
                for (int r = 0; r < 4; r++) {
                    int key = kb + sub * 16 + qd * 4 + r;
                    float pv = (key <= qrow) ? __expf(S[sub][r]) : 0.f;
                    S[sub][r] = pv;
                    lsum += pv;
                }
        } else {
            #pragma unroll
            for (int sub = 0; sub < 4; sub++)
                #pragma unroll
                for (int r = 0; r < 4; r++) {
                    float pv = __expf(S[sub][r]);
                    S[sub][r] = pv;
                    lsum += pv;
                }
        }

        // P^T: C-layout -> LDS (4x b64 writes) -> B-layout (2x b128 reads)
        #pragma unroll
        for (int sub = 0; sub < 4; sub++) {
            uint2 d;
            d.x = (unsigned)f2bf_fast(S[sub][0]) | ((unsigned)f2bf_fast(S[sub][1]) << 16);
            d.y = (unsigned)f2bf_fast(S[sub][2]) | ((unsigned)f2bf_fast(S[sub][3]) << 16);
            *(uint2*)(pw + sub * 16 + qd * 4) = d;
        }
        bf16x8 pf0 = *(const bf16x8*)(pw + qd * 8);
        bf16x8 pf1 = *(const bf16x8*)(pw + 32 + qd * 8);

        // O^T += V^T . P^T (K-dim = 64 keys = 2 MFMA k-steps)
        #pragma unroll
        for (int nt = 0; nt < 4; nt++) {
            O[nt] = __builtin_amdgcn_mfma_f32_16x16x32_bf16(vf[nt * 2 + 0], pf0, O[nt], 0, 0, 0);
            O[nt] = __builtin_amdgcn_mfma_f32_16x16x32_bf16(vf[nt * 2 + 1], pf1, O[nt], 0, 0, 0);
        }
    }

    // ---- cross-wave fp32 reduction, 4 -> 2 -> 1 per tile ----
    f32x4* red  = (f32x4*)pool;                  // 4 slots x 256 f32x4 (16 KB)
    float* lred = (float*)(pool + 16384);        // 4 slots x 64 f32
    __syncthreads();                             // Pw fully dead block-wide
    if (ws >= 2) {
        int sl = ts * 2 + (ws - 2);
        f32x4* rs = red + (size_t)sl * 256;
        #pragma unroll
        for (int nt = 0; nt < 4; nt++) rs[nt * 64 + lane] = O[nt];
        lred[sl * 64 + lane] = lsum;
    }
    __syncthreads();
    if (ws < 2) {
        int sl = ts * 2 + ws;
        f32x4* rs = red + (size_t)sl * 256;
        #pragma unroll
        for (int nt = 0; nt < 4; nt++) O[nt] += rs[nt * 64 + lane];
        lsum += lred[sl * 64 + lane];
    }
    __syncthreads();
    if (ws == 1) {
        int sl = ts * 2;
        f32x4* rs = red + (size_t)sl * 256;
        #pragma unroll
        for (int nt = 0; nt < 4; nt++) rs[nt * 64 + lane] = O[nt];
        lred[sl * 64 + lane] = lsum;
    }
    __syncthreads();
    if (ws == 0) {
        int sl = ts * 2;
        f32x4* rs = red + (size_t)sl * 256;
        #pragma unroll
        for (int nt = 0; nt < 4; nt++) O[nt] += rs[nt * 64 + lane];
        lsum += lred[sl * 64 + lane];
        // fold the 4 qd partial row-sums -> full denominator per row
        lsum += __shfl_xor(lsum, 16, 64);
        lsum += __shfl_xor(lsum, 32, 64);
        float li = 1.f / lsum;
        #pragma unroll
        for (int nt = 0; nt < 4; nt++) {
            f32x4 o = O[nt] * li;
            *(f32x4*)(out + (size_t)grow * HS_ + nt * 16 + qd * 4) = o;
        }
    }
}

// ---------------------------------------------------------------------------
extern "C" void kernel_launch(void* const* d_in, const int* in_sizes, int n_in,
                              void* d_out, int out_size, void* d_ws, size_t ws_size,
                              hipStream_t stream) {
    const float* x  = (const float*)d_in[0];
    const float* Wq = (const float*)d_in[1];
    const float* Wk = (const float*)d_in[2];
    const float* Wv = (const float*)d_in[3];
    float* out = (float*)d_out;

    ushort_t* wt  = (ushort_t*)d_ws;                    // 192*1024
    ushort_t* qws = wt  + (size_t)NCAT * C_;            // 8192*64
    ushort_t* kws = qws + (size_t)M_ * HS_;
    ushort_t* vt  = kws + (size_t)M_ * HS_;

    wconv_kernel<<<NCAT * C_ / (256 * 4), 256, 0, stream>>>(Wq, Wk, Wv, wt);
    proj_kernel<<<256, 512, 0, stream>>>(x, wt, qws, kws, vt);
    flash_kernel<<<dim3(64, 4), 512, 0, stream>>>(qws, kws, vt, out);
}

// Round 8
// 106.333 us; speedup vs baseline: 1.2618x; 1.2618x over previous
//
#include <hip/hip_runtime.h>
#include <math.h>

// Problem constants
#define B_  4
#define T_  2048
#define C_  1024
#define HS_ 64
#define M_  (B_*T_)   // 8192 rows
#define NCAT 192
#define SCALE_ 0.03125f   // C^-0.5
#define XPAD 1032         // xs row stride in bf16 elems (2064 B = 16B-aligned, word-stride 516 ≡ 4 mod 32 -> min-cycle b128 reads)

typedef unsigned short ushort_t;
typedef short bf16x8 __attribute__((ext_vector_type(8)));
typedef float f32x4 __attribute__((ext_vector_type(4)));

static __device__ __forceinline__ unsigned short f2bf(float f) {   // RNE (for inputs)
    union { float f; unsigned int u; } c; c.f = f;
    unsigned int u = c.u;
    return (unsigned short)((u + 0x7FFFu + ((u >> 16) & 1u)) >> 16);
}
static __device__ __forceinline__ unsigned short f2bf_fast(float f) { // 2-op round
    union { float f; unsigned int u; } c; c.f = f;
    return (unsigned short)((c.u + 0x8000u) >> 16);
}

// ---------------------------------------------------------------------------
// Kernel 1: W -> wtp FRAGMENT-PACKED: wtp[((c*12+nt)*64+l)*8+e] =
//   W_sel[(c*32+(l>>4)*8+e)*64 + (nt&3)*16+(l&15)]  (c=k/32 chunk, nt=tile)
// so proj's B-fragment load is a single coalesced 16B/lane read.
// Reads of W are full-line coalesced (16 consecutive n x 4 k-rows per instr).
// 96 blocks x 256 thr; wave w handles group g = blk*4+w (384 groups).
// ---------------------------------------------------------------------------
__global__ void wconv_kernel(const float* __restrict__ Wq, const float* __restrict__ Wk,
                             const float* __restrict__ Wv, ushort_t* __restrict__ wtp) {
    int l = threadIdx.x & 63;
    int g = blockIdx.x * 4 + (threadIdx.x >> 6);   // 0..383 = c*12+nt
    int c  = g / 12;
    int nt = g % 12;
    const float* W = (nt < 4) ? Wq : (nt < 8) ? Wk : Wv;
    int nn = (nt & 3) * 16 + (l & 15);
    int k0 = c * 32 + (l >> 4) * 8;
    union { bf16x8 v; ushort_t u[8]; } pk;
    #pragma unroll
    for (int e = 0; e < 8; e++)
        pk.u[e] = f2bf(W[(size_t)(k0 + e) * HS_ + nn]);
    *(bf16x8*)(wtp + ((size_t)g * 64 + l) * 8) = pk.v;
}

// ---------------------------------------------------------------------------
// Kernel 2: QKV projection — R1's barrier-free split-K structure (grid 512,
// 512 thr = 8 K-slice waves, 16 waves/CU) with both gather costs removed:
//  - x panel (16x1024) staged to LDS ONCE, coalesced float4 (8/thread, all
//    in flight), f2bf during staging; ONE barrier; A-frags = ds_read_b128
//    (XPAD -> every bank exactly 8 words = minimum, conflict-free).
//  - B-frags from fragment-packed wtp: 16B/lane coalesced L2 stream (the
//    old 16-line gathers are gone).
// Main loop: 4 x {1 A-read + 12 B-loads + 12 MFMA}, NO barriers.
// Then verified 3-round LDS tree reduce (red reuses pool after a sync)
// and the identical epilogue. Q pre-scaled. V transposed [b][d][t].
// ---------------------------------------------------------------------------
__global__ __launch_bounds__(512, 4) void proj_kernel(const float* __restrict__ x,
    const ushort_t* __restrict__ wtp,
    ushort_t* __restrict__ qws, ushort_t* __restrict__ kws, ushort_t* __restrict__ vt) {
    __shared__ __align__(16) unsigned char pool[49152];   // xs(33024B) then red(49152B)

    int tid  = threadIdx.x;
    int wid  = tid >> 6;       // K-slice 0..7
    int lane = tid & 63;
    int qd   = lane >> 4;
    int lq   = lane & 15;
    int r0   = blockIdx.x * 16;    // 512 rowgroups of 16

    // ---- stage x panel: 16 rows x 1024 f32 -> bf16 LDS, fully coalesced ----
    ushort_t* xs = (ushort_t*)pool;
    {
        float4 xv[8];
        #pragma unroll
        for (int j = 0; j < 8; j++) {
            int flat4 = j * 512 + tid;          // 0..4095 (256 float4/row)
            int row   = flat4 >> 8;
            int c4    = flat4 & 255;
            xv[j] = *(const float4*)(x + (size_t)(r0 + row) * C_ + c4 * 4);
        }
        #pragma unroll
        for (int j = 0; j < 8; j++) {
            int flat4 = j * 512 + tid;
            int row   = flat4 >> 8;
            int c4    = flat4 & 255;
            uint2 p;
            p.x = (unsigned)f2bf(xv[j].x) | ((unsigned)f2bf(xv[j].y) << 16);
            p.y = (unsigned)f2bf(xv[j].z) | ((unsigned)f2bf(xv[j].w) << 16);
            *(uint2*)(xs + row * XPAD + c4 * 4) = p;
        }
    }
    __syncthreads();

    // ---- barrier-free main loop ----
    f32x4 acc[12];
    #pragma unroll
    for (int i = 0; i < 12; i++) acc[i] = (f32x4){0.f,0.f,0.f,0.f};

    const ushort_t* xrow = xs + lq * XPAD + wid * 128 + qd * 8;
    #pragma unroll
    for (int i = 0; i < 4; i++) {
        bf16x8 af = *(const bf16x8*)(xrow + i * 32);
        #pragma unroll
        for (int nt = 0; nt < 12; nt++) {
            bf16x8 bv = *(const bf16x8*)(wtp +
                (((size_t)(wid * 4 + i) * 12 + nt) * 64 + lane) * 8);
            acc[nt] = __builtin_amdgcn_mfma_f32_16x16x32_bf16(af, bv, acc[nt], 0, 0, 0);
        }
    }

    // ---- tree reduce 8 -> 4 -> 2 -> 1 (red reuses pool; xs dead) ----
    __syncthreads();                                    // all xs reads done
    f32x4 (*red)[12 * 64] = (f32x4 (*)[12 * 64])pool;   // 4 slots, 49152 B
    if (wid >= 4) {
        #pragma unroll
        for (int nt = 0; nt < 12; nt++) red[wid - 4][nt * 64 + lane] = acc[nt];
    }
    __syncthreads();
    if (wid < 4) {
        #pragma unroll
        for (int nt = 0; nt < 12; nt++) acc[nt] += red[wid][nt * 64 + lane];
    }
    __syncthreads();
    if (wid == 2 || wid == 3) {
        #pragma unroll
        for (int nt = 0; nt < 12; nt++) red[wid][nt * 64 + lane] = acc[nt];
    }
    __syncthreads();
    if (wid < 2) {
        #pragma unroll
        for (int nt = 0; nt < 12; nt++) acc[nt] += red[wid + 2][nt * 64 + lane];
    }
    __syncthreads();
    if (wid == 1) {
        #pragma unroll
        for (int nt = 0; nt < 12; nt++) red[0][nt * 64 + lane] = acc[nt];
    }
    __syncthreads();
    if (wid == 0) {
        #pragma unroll
        for (int nt = 0; nt < 12; nt++) {
            acc[nt] += red[0][nt * 64 + lane];
            int outn = nt >> 2;            // 0=Q 1=K 2=V
            int col  = (nt & 3) * 16 + lq; // 0..63
            #pragma unroll
            for (int r = 0; r < 4; r++) {
                int row = r0 + qd * 4 + r;
                float v = acc[nt][r];
                if (outn == 0) v *= SCALE_;           // pre-scale Q
                ushort_t val = f2bf(v);
                if (outn == 0)      qws[(size_t)row * HS_ + col] = val;
                else if (outn == 1) kws[(size_t)row * HS_ + col] = val;
                else {
                    int b = row >> 11, t = row & 2047;
                    vt[((size_t)b * 64 + col) * T_ + t] = val;
                }
            }
        }
    }
}

// ---------------------------------------------------------------------------
// Kernel 3: balanced-pair causal flash, 512-thread blocks (8 waves).
// (Verified R6 structure, unchanged.)
// ---------------------------------------------------------------------------
__global__ __launch_bounds__(512, 2) void flash_kernel(const ushort_t* __restrict__ qws,
    const ushort_t* __restrict__ kws, const ushort_t* __restrict__ vt,
    float* __restrict__ out) {
    // pool: during k-loop = per-wave Pw[8][16*72] bf16 (18432 B);
    // after k-loop (sync'd) = f32x4 red[4][4*64] (16384 B) + float lred[4][64]
    __shared__ __align__(16) unsigned char pool[18432];

    int tid  = threadIdx.x;
    int wid  = tid >> 6;      // 0..7
    int lane = tid & 63;
    int qd   = lane >> 4;
    int lq   = lane & 15;
    int ts   = wid >> 2;      // 0 = tile p, 1 = tile 127-p
    int ws   = wid & 3;       // key-slice 0..3

    int batch = blockIdx.y;
    int p     = blockIdx.x;
    int tile  = ts ? (127 - p) : p;
    int q0    = tile * 16;
    int qrow  = q0 + lq;
    int grow  = batch * T_ + qrow;
    int nU    = (tile + 4) >> 2;    // 64-key units covering keys [0, q0+16)

    bf16x8 qf[2];
    #pragma unroll
    for (int st = 0; st < 2; st++)
        qf[st] = *(const bf16x8*)(qws + (size_t)grow * HS_ + st * 32 + qd * 8);

    float lsum = 0.f;
    f32x4 O[4];
    #pragma unroll
    for (int nt = 0; nt < 4; nt++) O[nt] = (f32x4){0.f,0.f,0.f,0.f};

    ushort_t* pw = (ushort_t*)pool + wid * 1152 + lq * 72;   // stride 72 bf16
    const ushort_t* kp    = kws + (size_t)batch * T_ * HS_;
    const ushort_t* vbase = vt  + (size_t)batch * 64 * T_;

    for (int u = ws; u < nU; u += 4) {
        int kb = u * 64;

        // batched loads: 8 K-frags + 8 V-frags, all 16 independent & in flight
        bf16x8 kf[8], vf[8];
        #pragma unroll
        for (int sub = 0; sub < 4; sub++)
            #pragma unroll
            for (int st = 0; st < 2; st++)
                kf[sub * 2 + st] = *(const bf16x8*)(kp + (size_t)(kb + sub * 16 + lq) * HS_ + st * 32 + qd * 8);
        #pragma unroll
        for (int nt = 0; nt < 4; nt++)
            #pragma unroll
            for (int kk = 0; kk < 2; kk++)
                vf[nt * 2 + kk] = *(const bf16x8*)(vbase + ((size_t)nt * 16 + lq) * T_ + kb + kk * 32 + qd * 8);

        // S^T = K . Q^T (Q pre-scaled): 4 sub-tiles of 16 keys
        f32x4 S[4];
        #pragma unroll
        for (int sub = 0; sub < 4; sub++) {
            f32x4 s = (f32x4){0.f,0.f,0.f,0.f};
            #pragma unroll
            for (int st = 0; st < 2; st++)
                s = __builtin_amdgcn_mfma_f32_16x16x32_bf16(kf[sub * 2 + st], qf[st], s, 0, 0, 0);
            S[sub] = s;
        }

        // P = exp(S); mask only when this 64-key unit can cross the diagonal
        if (kb + 64 > q0) {
            #pragma unroll
            for (int sub = 0; sub < 4; sub++)
                #pragma unroll
                for (int r = 0; r < 4; r++) {
                    int key = kb + sub * 16 + qd * 4 + r;
                    float pv = (key <= qrow) ? __expf(S[sub][r]) : 0.f;
                    S[sub][r] = pv;
                    lsum += pv;
                }
        } else {
            #pragma unroll
            for (int sub = 0; sub < 4; sub++)
                #pragma unroll
                for (int r = 0; r < 4; r++) {
                    float pv = __expf(S[sub][r]);
                    S[sub][r] = pv;
                    lsum += pv;
                }
        }

        // P^T: C-layout -> LDS (4x b64 writes) -> B-layout (2x b128 reads)
        #pragma unroll
        for (int sub = 0; sub < 4; sub++) {
            uint2 d;
            d.x = (unsigned)f2bf_fast(S[sub][0]) | ((unsigned)f2bf_fast(S[sub][1]) << 16);
            d.y = (unsigned)f2bf_fast(S[sub][2]) | ((unsigned)f2bf_fast(S[sub][3]) << 16);
            *(uint2*)(pw + sub * 16 + qd * 4) = d;
        }
        bf16x8 pf0 = *(const bf16x8*)(pw + qd * 8);
        bf16x8 pf1 = *(const bf16x8*)(pw + 32 + qd * 8);

        // O^T += V^T . P^T (K-dim = 64 keys = 2 MFMA k-steps)
        #pragma unroll
        for (int nt = 0; nt < 4; nt++) {
            O[nt] = __builtin_amdgcn_mfma_f32_16x16x32_bf16(vf[nt * 2 + 0], pf0, O[nt], 0, 0, 0);
            O[nt] = __builtin_amdgcn_mfma_f32_16x16x32_bf16(vf[nt * 2 + 1], pf1, O[nt], 0, 0, 0);
        }
    }

    // ---- cross-wave fp32 reduction, 4 -> 2 -> 1 per tile ----
    f32x4* red  = (f32x4*)pool;                  // 4 slots x 256 f32x4 (16 KB)
    float* lred = (float*)(pool + 16384);        // 4 slots x 64 f32
    __syncthreads();                             // Pw fully dead block-wide
    if (ws >= 2) {
        int sl = ts * 2 + (ws - 2);
        f32x4* rs = red + (size_t)sl * 256;
        #pragma unroll
        for (int nt = 0; nt < 4; nt++) rs[nt * 64 + lane] = O[nt];
        lred[sl * 64 + lane] = lsum;
    }
    __syncthreads();
    if (ws < 2) {
        int sl = ts * 2 + ws;
        f32x4* rs = red + (size_t)sl * 256;
        #pragma unroll
        for (int nt = 0; nt < 4; nt++) O[nt] += rs[nt * 64 + lane];
        lsum += lred[sl * 64 + lane];
    }
    __syncthreads();
    if (ws == 1) {
        int sl = ts * 2;
        f32x4* rs = red + (size_t)sl * 256;
        #pragma unroll
        for (int nt = 0; nt < 4; nt++) rs[nt * 64 + lane] = O[nt];
        lred[sl * 64 + lane] = lsum;
    }
    __syncthreads();
    if (ws == 0) {
        int sl = ts * 2;
        f32x4* rs = red + (size_t)sl * 256;
        #pragma unroll
        for (int nt = 0; nt < 4; nt++) O[nt] += rs[nt * 64 + lane];
        lsum += lred[sl * 64 + lane];
        // fold the 4 qd partial row-sums -> full denominator per row
        lsum += __shfl_xor(lsum, 16, 64);
        lsum += __shfl_xor(lsum, 32, 64);
        float li = 1.f / lsum;
        #pragma unroll
        for (int nt = 0; nt < 4; nt++) {
            f32x4 o = O[nt] * li;
            *(f32x4*)(out + (size_t)grow * HS_ + nt * 16 + qd * 4) = o;
        }
    }
}

// ---------------------------------------------------------------------------
extern "C" void kernel_launch(void* const* d_in, const int* in_sizes, int n_in,
                              void* d_out, int out_size, void* d_ws, size_t ws_size,
                              hipStream_t stream) {
    const float* x  = (const float*)d_in[0];
    const float* Wq = (const float*)d_in[1];
    const float* Wk = (const float*)d_in[2];
    const float* Wv = (const float*)d_in[3];
    float* out = (float*)d_out;

    ushort_t* wtp = (ushort_t*)d_ws;                    // 384*64*8 = 196608 bf16
    ushort_t* qws = wtp + (size_t)384 * 64 * 8;
    ushort_t* kws = qws + (size_t)M_ * HS_;
    ushort_t* vt  = kws + (size_t)M_ * HS_;

    wconv_kernel<<<96, 256, 0, stream>>>(Wq, Wk, Wv, wtp);
    proj_kernel<<<512, 512, 0, stream>>>(x, wtp, qws, kws, vt);
    flash_kernel<<<dim3(64, 4), 512, 0, stream>>>(qws, kws, vt, out);
}